// Round 1
// baseline (404.646 us; speedup 1.0000x reference)
//
#include <hip/hip_runtime.h>

// Problem constants (from setup_inputs): B=64, C=3, H=W=512, patch 16x16,
// nearest-upsample scale = 512/16 = 32, widen buf = 16.
#define HH 512
#define WW 512
#define PH 16
#define PW 16
#define BATCH 64
#define CCH 3
#define W4 (WW / 4)   // 128 float4 per row

// Kernel 1: per-batch bbox of nonzero patch cells -> widened pixel rect.
// One block (256 threads) per batch; cell (r,c) = (tid>>4, tid&15).
// Matches reference argmax-of-all-false degenerate case: no nonzero cell
// => bbox = full image.
__global__ void bbox_kernel(const int* __restrict__ patch,
                            const int* __restrict__ widen_p,
                            int4* __restrict__ rects) {
    __shared__ int s_rmin, s_rmax, s_cmin, s_cmax;
    const int t = threadIdx.x;
    if (t == 0) { s_rmin = 1 << 30; s_rmax = -1; s_cmin = 1 << 30; s_cmax = -1; }
    __syncthreads();
    const int b = blockIdx.x;
    const int v = patch[b * (PH * PW) + t];
    if (v != 0) {
        const int r = t >> 4, c = t & 15;
        atomicMin(&s_rmin, r);
        atomicMax(&s_rmax, r);
        atomicMin(&s_cmin, c);
        atomicMax(&s_cmax, c);
    }
    __syncthreads();
    if (t == 0) {
        // degenerate (no nonzero): argmax(all-false)=0 on both ends
        // => h_min=0, h_max=H-1  => patch bbox = full grid
        const int rmin = (s_rmax < 0) ? 0 : s_rmin;
        const int rmax = (s_rmax < 0) ? (PH - 1) : s_rmax;
        const int cmin = (s_cmax < 0) ? 0 : s_cmin;
        const int cmax = (s_cmax < 0) ? (PW - 1) : s_cmax;
        const int wd = *widen_p;
        int hs = 32 * rmin - wd;            if (hs < 0) hs = 0;
        int he = 32 * rmax + 31 + wd + 1;   if (he > HH) he = HH;
        int ws = 32 * cmin - wd;            if (ws < 0) ws = 0;
        int we = 32 * cmax + 31 + wd + 1;   if (we > WW) we = WW;
        rects[b] = make_int4(hs, he, ws, we);
    }
}

// Kernel 2: float4-vectorized select. grid = (H*W4/256, B*C).
// Rect x-bounds are multiples of 16 => a float4 (x%4==0) never straddles
// the boundary, so the inside/outside branch is per-thread uniform and
// each output element costs exactly one input read.
__global__ void apply_kernel(const float4* __restrict__ img,
                             const float4* __restrict__ noise,
                             const int* __restrict__ patch,
                             const int* __restrict__ widen_p,
                             const int4* __restrict__ rects,
                             float4* __restrict__ out) {
    const int p  = blockIdx.x * blockDim.x + threadIdx.x;  // 0 .. H*W4-1
    const int bc = blockIdx.y;                             // 0 .. B*C-1
    const int b  = bc / CCH;
    const int y  = p >> 7;          // p / W4
    const int x  = (p & (W4 - 1)) << 2;
    const long long i = (long long)bc * (HH * W4) + p;

    const int wd = *widen_p;
    bool inside;
    if (wd > 0) {
        const int4 r = rects[b];
        inside = (y >= r.x) && (y < r.y) && (x >= r.z) && (x < r.w);
    } else {
        // widen==0: mask is the raw nearest-upsampled patch map
        inside = patch[b * (PH * PW) + (y >> 5) * PW + (x >> 5)] != 0;
    }

    float4 o;
    if (inside) {
        o = img[i];
    } else {
        const float4 n = noise[i];
        o.x = fminf(fmaxf(n.x * 0.2f + 0.5f, 0.0f), 1.0f);
        o.y = fminf(fmaxf(n.y * 0.2f + 0.5f, 0.0f), 1.0f);
        o.z = fminf(fmaxf(n.z * 0.2f + 0.5f, 0.0f), 1.0f);
        o.w = fminf(fmaxf(n.w * 0.2f + 0.5f, 0.0f), 1.0f);
    }
    out[i] = o;
}

extern "C" void kernel_launch(void* const* d_in, const int* in_sizes, int n_in,
                              void* d_out, int out_size, void* d_ws, size_t ws_size,
                              hipStream_t stream) {
    const float* img   = (const float*)d_in[0];   // [B,C,H,W] f32
    const int*   patch = (const int*)d_in[1];     // [B,16,16] i32
    const float* noise = (const float*)d_in[2];   // [B,C,H,W] f32
    const int*   widen = (const int*)d_in[3];     // scalar i32

    int4* rects = (int4*)d_ws;                    // 64 * 16 B = 1 KB

    bbox_kernel<<<BATCH, PH * PW, 0, stream>>>(patch, widen, rects);

    dim3 grid(HH * W4 / 256, BATCH * CCH);        // (256, 192)
    apply_kernel<<<grid, 256, 0, stream>>>((const float4*)img,
                                           (const float4*)noise,
                                           patch, widen, rects,
                                           (float4*)d_out);
}